// Round 1
// baseline (15999.576 us; speedup 1.0000x reference)
//
#include <hip/hip_runtime.h>
#include <math.h>

#define TAU 6.283185307179586f
#define N576 576
#define PLANE 331776      // 576*576
#define MAPSZ 102400      // 16*16*20*20

// ---------------- Stage 1: signal -> spectrum (per 24x24 field) ----------------
__device__ inline void dft24(const float2* in, float2* out, int t, float sgn, bool firstAxis) {
  int r = t / 24, c = t % 24;
  int kk = firstAxis ? r : c;
  float2 acc = make_float2(0.f, 0.f);
  for (int n = 0; n < 24; ++n) {
    float ang = sgn * (TAU / 24.f) * (float)((kk * n) % 24);
    float s, co;
    sincosf(ang, &s, &co);
    float2 v = firstAxis ? in[n * 24 + c] : in[r * 24 + n];
    acc.x += v.x * co - v.y * s;
    acc.y += v.x * s + v.y * co;
  }
  out[t] = acc;
}

__global__ void spectrum_kernel(const float* __restrict__ sig, float2* __restrict__ spec) {
  __shared__ float2 b0[576];
  __shared__ float2 b1[576];
  int f = blockIdx.x;         // 0..31  (c*2+s)
  int t = threadIdx.x;        // 0..575
  int r = t / 24, c = t % 24;
  b0[t] = make_float2(sig[f * 576 + t], 0.f);
  __syncthreads();
  // F = fft2(signal)
  dft24(b0, b1, t, -1.f, false); __syncthreads();
  dft24(b1, b0, t, -1.f, true);  __syncthreads();
  // G = F / r_shift / 5   (r_shift[u,v] = r[(u+12)%24,(v+12)%24], r[p,q]=1+(p-11)^2+(q-11)^2)
  {
    int p2 = (r + 12) % 24 - 11;
    int q2 = (c + 12) % 24 - 11;
    float rr = (float)(1 + p2 * p2 + q2 * q2) * 5.f;
    float2 v = b0[t];
    b0[t] = make_float2(v.x / rr, v.y / rr);
  }
  __syncthreads();
  // wt = ifft2(G) * window   (unnormalized inverse, fold 1/576 into window mult)
  dft24(b0, b1, t, +1.f, false); __syncthreads();
  dft24(b1, b0, t, +1.f, true);  __syncthreads();
  {
    float winr = 0.5f * (1.f - cosf(TAU * (float)r / 24.f));
    float winc = 0.5f * (1.f - cosf(TAU * (float)c / 24.f));
    float w = winr * winc * (1.f / 576.f);
    float2 v = b0[t];
    b0[t] = make_float2(v.x * w, v.y * w);
  }
  __syncthreads();
  // spectrum = roll(fft2(wt), (12,12))
  dft24(b0, b1, t, -1.f, false); __syncthreads();
  dft24(b1, b0, t, -1.f, true);  __syncthreads();
  int p = (r + 12) % 24, q = (c + 12) % 24;
  spec[f * 576 + p * 24 + q] = b0[t];
}

// ---------------- Stage 2: build B = A / 2^s ----------------
// A[c,(i,j),(a,b)] = -i*( S0[11-i+a, 11-j+b]*(a-11) + S1[11-i+a, 11-j+b]*(b-11) )  (0 if OOB)
__global__ void build_B(const float2* __restrict__ spec, float* __restrict__ Br,
                        float* __restrict__ Bi, int c0, float scale) {
  int idx = blockIdx.x * 256 + threadIdx.x;   // 0..331775
  int cl = blockIdx.y;
  int c = c0 + cl;
  int row = idx / N576, col = idx % N576;
  int i = row / 24, j = row % 24, a = col / 24, b = col % 24;
  int u = 11 - i + a, v = 11 - j + b;
  float br = 0.f, bi = 0.f;
  if (u >= 0 && u < 24 && v >= 0 && v < 24) {
    float2 s0 = spec[(c * 2 + 0) * 576 + u * 24 + v];
    float2 s1 = spec[(c * 2 + 1) * 576 + u * 24 + v];
    float kx = (float)(a - 11), ky = (float)(b - 11);
    float xr = s0.x * kx + s1.x * ky;
    float xi = s0.y * kx + s1.y * ky;
    // -i*(xr + i*xi) = xi - i*xr
    br = xi * scale;
    bi = -xr * scale;
  }
  Br[(size_t)cl * PLANE + idx] = br;
  Bi[(size_t)cl * PLANE + idx] = bi;
}

// X = I + B*invK
__global__ void init_X(const float* __restrict__ Br, const float* __restrict__ Bi,
                       float* __restrict__ Xr, float* __restrict__ Xi, float invK) {
  int idx = blockIdx.x * 256 + threadIdx.x;
  int cl = blockIdx.y;
  int row = idx / N576, col = idx % N576;
  float d = (row == col) ? 1.f : 0.f;
  Xr[(size_t)cl * PLANE + idx] = Br[(size_t)cl * PLANE + idx] * invK + d;
  Xi[(size_t)cl * PLANE + idx] = Bi[(size_t)cl * PLANE + idx] * invK;
}

// ---------------- Stage 3: batched complex GEMM  D = alpha*(A*B) + delta*I ----------------
__global__ __launch_bounds__(256) void cgemm(
    const float* __restrict__ Ar, const float* __restrict__ Ai,
    const float* __restrict__ Br, const float* __restrict__ Bi,
    float* __restrict__ Dr, float* __restrict__ Di, float alpha, float delta) {
  __shared__ __align__(16) float AsR[16][68];
  __shared__ __align__(16) float AsI[16][68];
  __shared__ __align__(16) float BsR[16][68];
  __shared__ __align__(16) float BsI[16][68];
  int cl = blockIdx.z;
  const float* ar = Ar + (size_t)cl * PLANE;
  const float* ai = Ai + (size_t)cl * PLANE;
  const float* br = Br + (size_t)cl * PLANE;
  const float* bi = Bi + (size_t)cl * PLANE;
  int tid = threadIdx.x;
  int tx = tid & 15, ty = tid >> 4;
  int rowBase = blockIdx.y * 64, colBase = blockIdx.x * 64;
  float accR[4][4] = {{0.f}}, accI[4][4] = {{0.f}};
  for (int k0 = 0; k0 < N576; k0 += 16) {
#pragma unroll
    for (int ii = 0; ii < 4; ++ii) {
      int l = tid + 256 * ii;
      int rr = l >> 4, kk = l & 15;
      AsR[kk][rr] = ar[(size_t)(rowBase + rr) * N576 + k0 + kk];
      AsI[kk][rr] = ai[(size_t)(rowBase + rr) * N576 + k0 + kk];
      int cc = l & 63, k2 = l >> 6;
      BsR[k2][cc] = br[(size_t)(k0 + k2) * N576 + colBase + cc];
      BsI[k2][cc] = bi[(size_t)(k0 + k2) * N576 + colBase + cc];
    }
    __syncthreads();
#pragma unroll
    for (int kk = 0; kk < 16; ++kk) {
      float4 aR = *(const float4*)&AsR[kk][ty * 4];
      float4 aI = *(const float4*)&AsI[kk][ty * 4];
      float4 bR = *(const float4*)&BsR[kk][tx * 4];
      float4 bI = *(const float4*)&BsI[kk][tx * 4];
      float arr[4] = {aR.x, aR.y, aR.z, aR.w};
      float aii[4] = {aI.x, aI.y, aI.z, aI.w};
      float brr[4] = {bR.x, bR.y, bR.z, bR.w};
      float bii[4] = {bI.x, bI.y, bI.z, bI.w};
#pragma unroll
      for (int i = 0; i < 4; ++i)
#pragma unroll
        for (int j = 0; j < 4; ++j) {
          accR[i][j] += arr[i] * brr[j] - aii[i] * bii[j];
          accI[i][j] += arr[i] * bii[j] + aii[i] * brr[j];
        }
    }
    __syncthreads();
  }
#pragma unroll
  for (int i = 0; i < 4; ++i)
#pragma unroll
    for (int j = 0; j < 4; ++j) {
      int row = rowBase + ty * 4 + i, col = colBase + tx * 4 + j;
      float d = (row == col) ? delta : 0.f;
      size_t o = (size_t)cl * PLANE + (size_t)row * N576 + col;
      Dr[o] = alpha * accR[i][j] + d;
      Di[o] = alpha * accI[i][j];
    }
}

// ---------------- Stage 4: slice + roll + separable DFTs ----------------
// passA: gather x3 from T and ifft (unnormalized, +) over v'
__global__ void passA(const float* __restrict__ Tr, const float* __restrict__ Ti,
                      float2* __restrict__ P) {
  int cl = blockIdx.y;
  int idx = blockIdx.x * 256 + threadIdx.x;     // 0..102399
  int v = idx % 20, u = (idx / 20) % 20, q = (idx / 400) % 16, p = idx / 6400;
  int pp = (p + 7) % 16;     // (p-9) mod 16
  int qq = (q + 7) % 16;
  int row = (pp + 5) * 24 + (qq + 5);
  int uu = (u + 9) % 20;     // (u-11) mod 20
  int aa = uu + 3;
  const float* tr = Tr + (size_t)cl * PLANE;
  const float* ti = Ti + (size_t)cl * PLANE;
  float2 acc = make_float2(0.f, 0.f);
  for (int vp = 0; vp < 20; ++vp) {
    int vv = (vp + 9) % 20;
    int col = aa * 24 + (vv + 3);
    float xr = tr[(size_t)row * N576 + col];
    float xi = ti[(size_t)row * N576 + col];
    float ang = (TAU / 20.f) * (float)((v * vp) % 20);
    float s, co;
    sincosf(ang, &s, &co);
    acc.x += xr * co - xi * s;
    acc.y += xr * s + xi * co;
  }
  P[(size_t)cl * MAPSZ + idx] = acc;
}

// passB: ifft (+) over u'
__global__ void passB(const float2* __restrict__ Pin, float2* __restrict__ Pout) {
  int cl = blockIdx.y;
  int idx = blockIdx.x * 256 + threadIdx.x;
  int v = idx % 20, u = (idx / 20) % 20, q = (idx / 400) % 16, p = idx / 6400;
  const float2* in = Pin + (size_t)cl * MAPSZ;
  float2 acc = make_float2(0.f, 0.f);
  for (int up = 0; up < 20; ++up) {
    float2 val = in[(p * 16 + q) * 400 + up * 20 + v];
    float ang = (TAU / 20.f) * (float)((u * up) % 20);
    float s, co;
    sincosf(ang, &s, &co);
    acc.x += val.x * co - val.y * s;
    acc.y += val.x * s + val.y * co;
  }
  Pout[(size_t)cl * MAPSZ + idx] = acc;
}

// passC: fft (-) over q'
__global__ void passC(const float2* __restrict__ Pin, float2* __restrict__ Pout) {
  int cl = blockIdx.y;
  int idx = blockIdx.x * 256 + threadIdx.x;
  int v = idx % 20, u = (idx / 20) % 20, q = (idx / 400) % 16, p = idx / 6400;
  const float2* in = Pin + (size_t)cl * MAPSZ;
  float2 acc = make_float2(0.f, 0.f);
  for (int qp = 0; qp < 16; ++qp) {
    float2 val = in[(p * 16 + qp) * 400 + u * 20 + v];
    float ang = -(TAU / 16.f) * (float)((q * qp) % 16);
    float s, co;
    sincosf(ang, &s, &co);
    acc.x += val.x * co - val.y * s;
    acc.y += val.x * s + val.y * co;
  }
  Pout[(size_t)cl * MAPSZ + idx] = acc;
}

// passD: fft (-) over p', take real, * (1/400), write m[c][o*400+k]
__global__ void passD(const float2* __restrict__ Pin, float* __restrict__ m_all, int c0) {
  int cl = blockIdx.y;
  int c = c0 + cl;
  int idx = blockIdx.x * 256 + threadIdx.x;
  int v = idx % 20, u = (idx / 20) % 20, q = (idx / 400) % 16, p = idx / 6400;
  const float2* in = Pin + (size_t)cl * MAPSZ;
  float acc = 0.f;
  for (int pp = 0; pp < 16; ++pp) {
    float2 val = in[(pp * 16 + q) * 400 + u * 20 + v];
    float ang = -(TAU / 16.f) * (float)((p * pp) % 16);
    float s, co;
    sincosf(ang, &s, &co);
    acc += val.x * co - val.y * s;
  }
  m_all[(size_t)c * MAPSZ + idx] = acc * (1.f / 400.f);
}

// ---------------- Stage 5: final GEMM  Y[b][n] = sum_k X[b][k]*M[n][k] ----------------
__global__ __launch_bounds__(256) void out_gemm(const float* __restrict__ X,
                                                const float* __restrict__ M,
                                                float* __restrict__ Y) {
  __shared__ __align__(16) float Xs[16][68];
  __shared__ __align__(16) float Ms[16][68];
  int tid = threadIdx.x;
  int tx = tid & 15, ty = tid >> 4;
  int bBase = blockIdx.y * 64, nBase = blockIdx.x * 64;
  float acc[4][4] = {{0.f}};
  for (int k0 = 0; k0 < 400; k0 += 16) {
#pragma unroll
    for (int ii = 0; ii < 4; ++ii) {
      int l = tid + 256 * ii;
      int rr = l >> 4, kk = l & 15;
      Xs[kk][rr] = X[(size_t)(bBase + rr) * 400 + k0 + kk];
      Ms[kk][rr] = M[(size_t)(nBase + rr) * 400 + k0 + kk];
    }
    __syncthreads();
#pragma unroll
    for (int kk = 0; kk < 16; ++kk) {
      float4 a4 = *(const float4*)&Xs[kk][ty * 4];
      float4 b4 = *(const float4*)&Ms[kk][tx * 4];
      float aa[4] = {a4.x, a4.y, a4.z, a4.w};
      float bb[4] = {b4.x, b4.y, b4.z, b4.w};
#pragma unroll
      for (int i = 0; i < 4; ++i)
#pragma unroll
        for (int j = 0; j < 4; ++j) acc[i][j] += aa[i] * bb[j];
    }
    __syncthreads();
  }
#pragma unroll
  for (int i = 0; i < 4; ++i)
#pragma unroll
    for (int j = 0; j < 4; ++j)
      Y[(size_t)(bBase + ty * 4 + i) * 4096 + nBase + tx * 4 + j] = acc[i][j];
}

// ---------------- Launcher ----------------
extern "C" void kernel_launch(void* const* d_in, const int* in_sizes, int n_in,
                              void* d_out, int out_size, void* d_ws, size_t ws_size,
                              hipStream_t stream) {
  const float* x = (const float*)d_in[0];     // (8192,1,20,20)
  const float* sig = (const float*)d_in[1];   // (16,2,24,24)
  float* out = (float*)d_out;                 // (8192,16,16,16)
  char* ws = (char*)d_ws;

  const size_t specBytes = 32ull * 576 * sizeof(float2);          // 147456
  const size_t mBytes = 16ull * MAPSZ * sizeof(float);            // 6553600
  const size_t fixed = specBytes + mBytes;                        // 6701056
  const size_t perCh = 6ull * PLANE * 4 + 2ull * MAPSZ * 8;       // 9601024

  int cg = 16;
  if (ws_size > fixed) {
    size_t av = (ws_size - fixed) / perCh;
    if (av < 16) cg = (av < 1) ? 1 : (int)av;
  } else {
    cg = 1;
  }

  float2* spec = (float2*)ws;
  float* m_all = (float*)(ws + specBytes);
  float* base = (float*)(ws + fixed);
  float* Br = base;
  float* Bi = Br + (size_t)cg * PLANE;
  float* X0r = Bi + (size_t)cg * PLANE;
  float* X0i = X0r + (size_t)cg * PLANE;
  float* X1r = X0i + (size_t)cg * PLANE;
  float* X1i = X1r + (size_t)cg * PLANE;
  float2* P0 = (float2*)(X1i + (size_t)cg * PLANE);
  float2* P1 = P0 + (size_t)cg * MAPSZ;

  spectrum_kernel<<<dim3(32), dim3(576), 0, stream>>>(sig, spec);

  const float scale = 1.f / 256.f;  // s = 8
  for (int c0 = 0; c0 < 16; c0 += cg) {
    int g = (16 - c0 < cg) ? (16 - c0) : cg;
    build_B<<<dim3(PLANE / 256, g), dim3(256), 0, stream>>>(spec, Br, Bi, c0, scale);
    init_X<<<dim3(PLANE / 256, g), dim3(256), 0, stream>>>(Br, Bi, X0r, X0i, 1.f / 6.f);
    float* xr = X0r; float* xi = X0i; float* yr = X1r; float* yi = X1i;
    // Horner: X <- I + (B*X)/k, k=5..1
    for (int k = 5; k >= 1; --k) {
      cgemm<<<dim3(9, 9, g), dim3(256), 0, stream>>>(Br, Bi, xr, xi, yr, yi,
                                                     1.f / (float)k, 1.f);
      float* t;
      t = xr; xr = yr; yr = t;
      t = xi; xi = yi; yi = t;
    }
    // 8 squarings
    for (int t8 = 0; t8 < 8; ++t8) {
      cgemm<<<dim3(9, 9, g), dim3(256), 0, stream>>>(xr, xi, xr, xi, yr, yi, 1.f, 0.f);
      float* t;
      t = xr; xr = yr; yr = t;
      t = xi; xi = yi; yi = t;
    }
    passA<<<dim3(400, g), dim3(256), 0, stream>>>(xr, xi, P0);
    passB<<<dim3(400, g), dim3(256), 0, stream>>>(P0, P1);
    passC<<<dim3(400, g), dim3(256), 0, stream>>>(P1, P0);
    passD<<<dim3(400, g), dim3(256), 0, stream>>>(P0, m_all, c0);
  }

  out_gemm<<<dim3(64, 128), dim3(256), 0, stream>>>(x, m_all, out);
}

// Round 2
// 2599.619 us; speedup vs baseline: 6.1546x; 6.1546x over previous
//
#include <hip/hip_runtime.h>
#include <hip/hip_bf16.h>
#include <math.h>

#define TAU 6.283185307179586f
#define N576 576
#define PLANE 331776      // 576*576
#define MAPSZ 102400      // 16*16*20*20
#define SETSTR ((size_t)4 * PLANE)   // elements per 4-plane split set

typedef __attribute__((ext_vector_type(8))) short short8;
typedef __attribute__((ext_vector_type(4))) float f32x4;

__device__ inline void bsplit(float v, __hip_bfloat16& h, __hip_bfloat16& l) {
  h = __float2bfloat16(v);
  l = __float2bfloat16(v - __bfloat162float(h));
}

__device__ inline void gld16(const void* g, const void* l) {
  __builtin_amdgcn_global_load_lds((const __attribute__((address_space(1))) unsigned*)g,
                                   (__attribute__((address_space(3))) unsigned*)l, 16, 0, 0);
}

// ---------------- Stage 1: signal -> spectrum (per 24x24 field) ----------------
__device__ inline void dft24(const float2* in, float2* out, int t, float sgn, bool firstAxis) {
  int r = t / 24, c = t % 24;
  int kk = firstAxis ? r : c;
  float2 acc = make_float2(0.f, 0.f);
  for (int n = 0; n < 24; ++n) {
    float ang = sgn * (TAU / 24.f) * (float)((kk * n) % 24);
    float s, co;
    sincosf(ang, &s, &co);
    float2 v = firstAxis ? in[n * 24 + c] : in[r * 24 + n];
    acc.x += v.x * co - v.y * s;
    acc.y += v.x * s + v.y * co;
  }
  out[t] = acc;
}

__global__ void spectrum_kernel(const float* __restrict__ sig, float2* __restrict__ spec) {
  __shared__ float2 b0[576];
  __shared__ float2 b1[576];
  int f = blockIdx.x;         // 0..31  (c*2+s)
  int t = threadIdx.x;        // 0..575
  int r = t / 24, c = t % 24;
  b0[t] = make_float2(sig[f * 576 + t], 0.f);
  __syncthreads();
  dft24(b0, b1, t, -1.f, false); __syncthreads();
  dft24(b1, b0, t, -1.f, true);  __syncthreads();
  {
    int p2 = (r + 12) % 24 - 11;
    int q2 = (c + 12) % 24 - 11;
    float rr = (float)(1 + p2 * p2 + q2 * q2) * 5.f;
    float2 v = b0[t];
    b0[t] = make_float2(v.x / rr, v.y / rr);
  }
  __syncthreads();
  dft24(b0, b1, t, +1.f, false); __syncthreads();
  dft24(b1, b0, t, +1.f, true);  __syncthreads();
  {
    float winr = 0.5f * (1.f - cosf(TAU * (float)r / 24.f));
    float winc = 0.5f * (1.f - cosf(TAU * (float)c / 24.f));
    float w = winr * winc * (1.f / 576.f);
    float2 v = b0[t];
    b0[t] = make_float2(v.x * w, v.y * w);
  }
  __syncthreads();
  dft24(b0, b1, t, -1.f, false); __syncthreads();
  dft24(b1, b0, t, -1.f, true);  __syncthreads();
  int p = (r + 12) % 24, q = (c + 12) % 24;
  spec[f * 576 + p * 24 + q] = b0[t];
}

// ---------------- Stage 2: build split B and X0 = I + B/6 (row-major planes) ----------------
// planes: 0 = Re-hi, 1 = Re-lo, 2 = Im-hi, 3 = Im-lo
__global__ void buildBX(const float2* __restrict__ spec, __hip_bfloat16* __restrict__ B,
                        __hip_bfloat16* __restrict__ X0, int c0, float scale) {
  int idx = blockIdx.x * 256 + threadIdx.x;   // 0..331775
  int cl = blockIdx.y;
  int c = c0 + cl;
  int row = idx / N576, col = idx % N576;
  int i = row / 24, j = row % 24, a = col / 24, b = col % 24;
  int u = 11 - i + a, v = 11 - j + b;
  float br = 0.f, bi = 0.f;
  if (u >= 0 && u < 24 && v >= 0 && v < 24) {
    float2 s0 = spec[(c * 2 + 0) * 576 + u * 24 + v];
    float2 s1 = spec[(c * 2 + 1) * 576 + u * 24 + v];
    float kx = (float)(a - 11), ky = (float)(b - 11);
    float xr = s0.x * kx + s1.x * ky;
    float xi = s0.y * kx + s1.y * ky;
    br = xi * scale;          // -i*(xr+i*xi) = xi - i*xr
    bi = -xr * scale;
  }
  size_t off = (size_t)cl * SETSTR + idx;
  __hip_bfloat16 h, l;
  bsplit(br, h, l); B[off] = h; B[off + PLANE] = l;
  bsplit(bi, h, l); B[off + 2 * PLANE] = h; B[off + 3 * PLANE] = l;
  float d = (row == col) ? 1.f : 0.f;
  bsplit(br * (1.f / 6.f) + d, h, l); X0[off] = h; X0[off + PLANE] = l;
  bsplit(bi * (1.f / 6.f), h, l);     X0[off + 2 * PLANE] = h; X0[off + 3 * PLANE] = l;
}

// ---------------- transpose the 4 split planes of a matrix set ----------------
__global__ __launch_bounds__(256) void transpose4(const __hip_bfloat16* __restrict__ src,
                                                  __hip_bfloat16* __restrict__ dst) {
  __shared__ __hip_bfloat16 tile[64][65];
  int cl = blockIdx.z;
  size_t off = (size_t)cl * SETSTR;
  int rB = blockIdx.y * 64, cB = blockIdx.x * 64;
  int tx = threadIdx.x & 63, ty = threadIdx.x >> 6;
  for (int p = 0; p < 4; ++p) {
    for (int li = 0; li < 16; ++li) {
      int r = ty * 16 + li;
      tile[r][tx] = src[off + (size_t)p * PLANE + (size_t)(rB + r) * N576 + cB + tx];
    }
    __syncthreads();
    for (int li = 0; li < 16; ++li) {
      int r = ty * 16 + li;
      dst[off + (size_t)p * PLANE + (size_t)(cB + r) * N576 + rB + tx] = tile[tx][r];
    }
    __syncthreads();
  }
}

// ---------------- Stage 3: batched split-complex MFMA GEMM ----------------
// D = alpha*(A*B) + delta*I,  A given row-major split planes, B given as BT (n-major, k contiguous).
// Output written in both layouts (row-major D, transposed DT), split form.
#define MFMA16(a, b, c) __builtin_amdgcn_mfma_f32_16x16x32_bf16(a, b, c, 0, 0, 0)

__global__ __launch_bounds__(256) void cgemm_mfma(
    const __hip_bfloat16* __restrict__ A, const __hip_bfloat16* __restrict__ BT,
    __hip_bfloat16* __restrict__ D, __hip_bfloat16* __restrict__ DT,
    float alpha, float delta) {
  __shared__ char lds[2][32768];   // per buf: A planes @ p*4096, B planes @ 16384+p*4096
  const int t = threadIdx.x;
  const int lane = t & 63;
  const int wid = t >> 6;
  const int wm = wid >> 1, wn = wid & 1;
  const int cl = blockIdx.z;
  const int rowBase = blockIdx.y * 64, colBase = blockIdx.x * 64;
  const size_t chOff = (size_t)cl * SETSTR;
  const __hip_bfloat16* Ab = A + chOff;
  const __hip_bfloat16* Bb = BT + chOff;

  // staging: thread t owns LDS 16B-chunk (row sm, slot t&3); fetches global chunk scg (XOR swizzle)
  const int sm = t >> 2;
  const int scg = (t & 3) ^ ((sm >> 1) & 3);
  const size_t gAoff = (size_t)(rowBase + sm) * N576 + scg * 8;
  const size_t gBoff = (size_t)(colBase + sm) * N576 + scg * 8;
  const int ldsWave = (t & 192) * 16;   // wave * 1024 bytes

  f32x4 accP[2][2] = {}, accN[2][2] = {}, accI[2][2] = {};

  auto STAGE = [&](int buf, int k0) {
#pragma unroll
    for (int p = 0; p < 4; ++p) {
      gld16(Ab + (size_t)p * PLANE + gAoff + k0, &lds[buf][p * 4096 + ldsWave]);
      gld16(Bb + (size_t)p * PLANE + gBoff + k0, &lds[buf][16384 + p * 4096 + ldsWave]);
    }
  };

  STAGE(0, 0);
  __syncthreads();

  int cur = 0;
#pragma unroll 1
  for (int ks = 0; ks < 18; ++ks) {
    if (ks < 17) STAGE(cur ^ 1, (ks + 1) * 32);
    short8 arh[2], arl[2], aih[2], ail[2];
    short8 brh[2], brl[2], bih[2], bil[2];
#pragma unroll
    for (int mi = 0; mi < 2; ++mi) {
      int r = wm * 32 + mi * 16 + (lane & 15);
      int ch = (lane >> 4) ^ ((r >> 1) & 3);
      const char* base = &lds[cur][(r * 4 + ch) * 16];
      arh[mi] = *(const short8*)(base);
      arl[mi] = *(const short8*)(base + 4096);
      aih[mi] = *(const short8*)(base + 8192);
      ail[mi] = *(const short8*)(base + 12288);
    }
#pragma unroll
    for (int ni = 0; ni < 2; ++ni) {
      int cc = wn * 32 + ni * 16 + (lane & 15);
      int ch = (lane >> 4) ^ ((cc >> 1) & 3);
      const char* base = &lds[cur][16384 + (cc * 4 + ch) * 16];
      brh[ni] = *(const short8*)(base);
      brl[ni] = *(const short8*)(base + 4096);
      bih[ni] = *(const short8*)(base + 8192);
      bil[ni] = *(const short8*)(base + 12288);
    }
#pragma unroll
    for (int mi = 0; mi < 2; ++mi)
#pragma unroll
      for (int ni = 0; ni < 2; ++ni) {
        accP[mi][ni] = MFMA16(arh[mi], brh[ni], accP[mi][ni]);
        accP[mi][ni] = MFMA16(arh[mi], brl[ni], accP[mi][ni]);
        accP[mi][ni] = MFMA16(arl[mi], brh[ni], accP[mi][ni]);
        accN[mi][ni] = MFMA16(aih[mi], bih[ni], accN[mi][ni]);
        accN[mi][ni] = MFMA16(aih[mi], bil[ni], accN[mi][ni]);
        accN[mi][ni] = MFMA16(ail[mi], bih[ni], accN[mi][ni]);
        accI[mi][ni] = MFMA16(arh[mi], bih[ni], accI[mi][ni]);
        accI[mi][ni] = MFMA16(arh[mi], bil[ni], accI[mi][ni]);
        accI[mi][ni] = MFMA16(arl[mi], bih[ni], accI[mi][ni]);
        accI[mi][ni] = MFMA16(aih[mi], brh[ni], accI[mi][ni]);
        accI[mi][ni] = MFMA16(aih[mi], brl[ni], accI[mi][ni]);
        accI[mi][ni] = MFMA16(ail[mi], brh[ni], accI[mi][ni]);
      }
    __syncthreads();
    cur ^= 1;
  }

  __hip_bfloat16* Dp = D + chOff;
  __hip_bfloat16* Tp = DT + chOff;
#pragma unroll
  for (int mi = 0; mi < 2; ++mi)
#pragma unroll
    for (int ni = 0; ni < 2; ++ni) {
      int rb = rowBase + wm * 32 + mi * 16 + (lane >> 4) * 4;
      int cc = colBase + wn * 32 + ni * 16 + (lane & 15);
#pragma unroll
      for (int j = 0; j < 4; ++j) {
        int r = rb + j;
        float vR = alpha * (accP[mi][ni][j] - accN[mi][ni][j]) + ((r == cc) ? delta : 0.f);
        float vI = alpha * accI[mi][ni][j];
        __hip_bfloat16 h, l;
        bsplit(vR, h, l);
        Dp[(size_t)r * N576 + cc] = h;
        Dp[PLANE + (size_t)r * N576 + cc] = l;
        Tp[(size_t)cc * N576 + r] = h;
        Tp[PLANE + (size_t)cc * N576 + r] = l;
        bsplit(vI, h, l);
        Dp[2 * PLANE + (size_t)r * N576 + cc] = h;
        Dp[3 * PLANE + (size_t)r * N576 + cc] = l;
        Tp[2 * PLANE + (size_t)cc * N576 + r] = h;
        Tp[3 * PLANE + (size_t)cc * N576 + r] = l;
      }
    }
}

// ---------------- Stage 4: slice + roll + separable DFTs ----------------
__global__ void passA(const __hip_bfloat16* __restrict__ X, float2* __restrict__ P) {
  int cl = blockIdx.y;
  int idx = blockIdx.x * 256 + threadIdx.x;     // 0..102399
  int v = idx % 20, u = (idx / 20) % 20, q = (idx / 400) % 16, p = idx / 6400;
  int pp = (p + 7) % 16;
  int qq = (q + 7) % 16;
  int row = (pp + 5) * 24 + (qq + 5);
  int uu = (u + 9) % 20;
  int aa = uu + 3;
  const __hip_bfloat16* tb = X + (size_t)cl * SETSTR;
  float2 acc = make_float2(0.f, 0.f);
  for (int vp = 0; vp < 20; ++vp) {
    int vv = (vp + 9) % 20;
    int col = aa * 24 + (vv + 3);
    size_t o = (size_t)row * N576 + col;
    float xr = __bfloat162float(tb[o]) + __bfloat162float(tb[PLANE + o]);
    float xi = __bfloat162float(tb[2 * PLANE + o]) + __bfloat162float(tb[3 * PLANE + o]);
    float ang = (TAU / 20.f) * (float)((v * vp) % 20);
    float s, co;
    sincosf(ang, &s, &co);
    acc.x += xr * co - xi * s;
    acc.y += xr * s + xi * co;
  }
  P[(size_t)cl * MAPSZ + idx] = acc;
}

__global__ void passB(const float2* __restrict__ Pin, float2* __restrict__ Pout) {
  int cl = blockIdx.y;
  int idx = blockIdx.x * 256 + threadIdx.x;
  int v = idx % 20, u = (idx / 20) % 20, q = (idx / 400) % 16, p = idx / 6400;
  const float2* in = Pin + (size_t)cl * MAPSZ;
  float2 acc = make_float2(0.f, 0.f);
  for (int up = 0; up < 20; ++up) {
    float2 val = in[(p * 16 + q) * 400 + up * 20 + v];
    float ang = (TAU / 20.f) * (float)((u * up) % 20);
    float s, co;
    sincosf(ang, &s, &co);
    acc.x += val.x * co - val.y * s;
    acc.y += val.x * s + val.y * co;
  }
  Pout[(size_t)cl * MAPSZ + idx] = acc;
}

__global__ void passC(const float2* __restrict__ Pin, float2* __restrict__ Pout) {
  int cl = blockIdx.y;
  int idx = blockIdx.x * 256 + threadIdx.x;
  int v = idx % 20, u = (idx / 20) % 20, q = (idx / 400) % 16, p = idx / 6400;
  const float2* in = Pin + (size_t)cl * MAPSZ;
  float2 acc = make_float2(0.f, 0.f);
  for (int qp = 0; qp < 16; ++qp) {
    float2 val = in[(p * 16 + qp) * 400 + u * 20 + v];
    float ang = -(TAU / 16.f) * (float)((q * qp) % 16);
    float s, co;
    sincosf(ang, &s, &co);
    acc.x += val.x * co - val.y * s;
    acc.y += val.x * s + val.y * co;
  }
  Pout[(size_t)cl * MAPSZ + idx] = acc;
}

__global__ void passD(const float2* __restrict__ Pin, float* __restrict__ m_all, int c0) {
  int cl = blockIdx.y;
  int c = c0 + cl;
  int idx = blockIdx.x * 256 + threadIdx.x;
  int v = idx % 20, u = (idx / 20) % 20, q = (idx / 400) % 16, p = idx / 6400;
  const float2* in = Pin + (size_t)cl * MAPSZ;
  float acc = 0.f;
  for (int pp = 0; pp < 16; ++pp) {
    float2 val = in[(pp * 16 + q) * 400 + u * 20 + v];
    float ang = -(TAU / 16.f) * (float)((p * pp) % 16);
    float s, co;
    sincosf(ang, &s, &co);
    acc += val.x * co - val.y * s;
  }
  m_all[(size_t)c * MAPSZ + idx] = acc * (1.f / 400.f);
}

// ---------------- Stage 5: final GEMM  Y[b][n] = sum_k X[b][k]*M[n][k] ----------------
__global__ __launch_bounds__(256) void out_gemm(const float* __restrict__ X,
                                                const float* __restrict__ M,
                                                float* __restrict__ Y) {
  __shared__ __align__(16) float Xs[16][68];
  __shared__ __align__(16) float Ms[16][68];
  int tid = threadIdx.x;
  int tx = tid & 15, ty = tid >> 4;
  int bBase = blockIdx.y * 64, nBase = blockIdx.x * 64;
  float acc[4][4] = {{0.f}};
  for (int k0 = 0; k0 < 400; k0 += 16) {
#pragma unroll
    for (int ii = 0; ii < 4; ++ii) {
      int l = tid + 256 * ii;
      int rr = l >> 4, kk = l & 15;
      Xs[kk][rr] = X[(size_t)(bBase + rr) * 400 + k0 + kk];
      Ms[kk][rr] = M[(size_t)(nBase + rr) * 400 + k0 + kk];
    }
    __syncthreads();
#pragma unroll
    for (int kk = 0; kk < 16; ++kk) {
      float4 a4 = *(const float4*)&Xs[kk][ty * 4];
      float4 b4 = *(const float4*)&Ms[kk][tx * 4];
      float aa[4] = {a4.x, a4.y, a4.z, a4.w};
      float bb[4] = {b4.x, b4.y, b4.z, b4.w};
#pragma unroll
      for (int i = 0; i < 4; ++i)
#pragma unroll
        for (int j = 0; j < 4; ++j) acc[i][j] += aa[i] * bb[j];
    }
    __syncthreads();
  }
#pragma unroll
  for (int i = 0; i < 4; ++i)
#pragma unroll
    for (int j = 0; j < 4; ++j)
      Y[(size_t)(bBase + ty * 4 + i) * 4096 + nBase + tx * 4 + j] = acc[i][j];
}

// ---------------- Launcher ----------------
extern "C" void kernel_launch(void* const* d_in, const int* in_sizes, int n_in,
                              void* d_out, int out_size, void* d_ws, size_t ws_size,
                              hipStream_t stream) {
  const float* x = (const float*)d_in[0];     // (8192,1,20,20)
  const float* sig = (const float*)d_in[1];   // (16,2,24,24)
  float* out = (float*)d_out;                 // (8192,16,16,16)
  char* ws = (char*)d_ws;

  const size_t specBytes = 32ull * 576 * sizeof(float2);          // 147456
  const size_t mBytes = 16ull * MAPSZ * sizeof(float);            // 6553600
  const size_t fixed = specBytes + mBytes;                        // 6701056
  const size_t setB = SETSTR * 2;                                 // bytes per split set (2654208)
  const size_t perCh = 6 * setB + 2ull * MAPSZ * 8;               // 17563648

  int cg = 1;
  if (ws_size > fixed) {
    size_t av = (ws_size - fixed) / perCh;
    cg = (av < 1) ? 1 : (av > 16 ? 16 : (int)av);
  }

  float2* spec = (float2*)ws;
  float* m_all = (float*)(ws + specBytes);
  __hip_bfloat16* Bst = (__hip_bfloat16*)(ws + fixed);
  __hip_bfloat16* BTst = Bst + (size_t)cg * SETSTR;
  __hip_bfloat16* X0 = BTst + (size_t)cg * SETSTR;
  __hip_bfloat16* X0T = X0 + (size_t)cg * SETSTR;
  __hip_bfloat16* X1 = X0T + (size_t)cg * SETSTR;
  __hip_bfloat16* X1T = X1 + (size_t)cg * SETSTR;
  float2* P0 = (float2*)(X1T + (size_t)cg * SETSTR);
  float2* P1 = P0 + (size_t)cg * MAPSZ;

  spectrum_kernel<<<dim3(32), dim3(576), 0, stream>>>(sig, spec);

  const float scale = 1.f / 256.f;  // s = 8 squarings
  for (int c0 = 0; c0 < 16; c0 += cg) {
    int g = (16 - c0 < cg) ? (16 - c0) : cg;
    buildBX<<<dim3(PLANE / 256, g), dim3(256), 0, stream>>>(spec, Bst, X0, c0, scale);
    transpose4<<<dim3(9, 9, g), dim3(256), 0, stream>>>(Bst, BTst);
    transpose4<<<dim3(9, 9, g), dim3(256), 0, stream>>>(X0, X0T);
    __hip_bfloat16 *xr = X0, *xt = X0T, *yr = X1, *yt = X1T;
    // Horner: X <- I + (B*X)/k, k=5..1
    for (int k = 5; k >= 1; --k) {
      cgemm_mfma<<<dim3(9, 9, g), dim3(256), 0, stream>>>(Bst, xt, yr, yt, 1.f / (float)k, 1.f);
      __hip_bfloat16* tmp;
      tmp = xr; xr = yr; yr = tmp;
      tmp = xt; xt = yt; yt = tmp;
    }
    // 8 squarings
    for (int t8 = 0; t8 < 8; ++t8) {
      cgemm_mfma<<<dim3(9, 9, g), dim3(256), 0, stream>>>(xr, xt, yr, yt, 1.f, 0.f);
      __hip_bfloat16* tmp;
      tmp = xr; xr = yr; yr = tmp;
      tmp = xt; xt = yt; yt = tmp;
    }
    passA<<<dim3(400, g), dim3(256), 0, stream>>>(xr, P0);
    passB<<<dim3(400, g), dim3(256), 0, stream>>>(P0, P1);
    passC<<<dim3(400, g), dim3(256), 0, stream>>>(P1, P0);
    passD<<<dim3(400, g), dim3(256), 0, stream>>>(P0, m_all, c0);
  }

  out_gemm<<<dim3(64, 128), dim3(256), 0, stream>>>(x, m_all, out);
}

// Round 3
// 2443.190 us; speedup vs baseline: 6.5486x; 1.0640x over previous
//
#include <hip/hip_runtime.h>
#include <hip/hip_bf16.h>
#include <math.h>

#define TAU 6.283185307179586f
#define NK 576                    // matrix dimension (K always exact: 18*32)
#define NPAD 640                  // padded row count for 128-row tiles
#define PLN ((size_t)NPAD * NK)   // elems per padded plane = 368640
#define SETSTR ((size_t)4 * PLN)  // elems per 4-plane split set
#define MAPSZ 102400              // 16*16*20*20
#define KOUT 416                  // padded K for output gemm (13*32)
#define XPL ((size_t)8192 * KOUT)
#define MPL ((size_t)4096 * KOUT)

typedef __attribute__((ext_vector_type(8))) short short8;
typedef __attribute__((ext_vector_type(4))) float f32x4;

__device__ inline void bsplit(float v, __hip_bfloat16& h, __hip_bfloat16& l) {
  h = __float2bfloat16(v);
  l = __float2bfloat16(v - __bfloat162float(h));
}
__device__ inline short braw(__hip_bfloat16 b) { return *reinterpret_cast<short*>(&b); }

__device__ inline void gld16(const void* g, const void* l) {
  __builtin_amdgcn_global_load_lds((const __attribute__((address_space(1))) unsigned*)g,
                                   (__attribute__((address_space(3))) unsigned*)l, 16, 0, 0);
}

#define MFMA16(a, b, c) __builtin_amdgcn_mfma_f32_16x16x32_bf16(a, b, c, 0, 0, 0)

// ---------------- Stage 1: signal -> spectrum ----------------
__device__ inline void dft24(const float2* in, float2* out, int t, float sgn, bool firstAxis) {
  int r = t / 24, c = t % 24;
  int kk = firstAxis ? r : c;
  float2 acc = make_float2(0.f, 0.f);
  for (int n = 0; n < 24; ++n) {
    float ang = sgn * (TAU / 24.f) * (float)((kk * n) % 24);
    float s, co;
    sincosf(ang, &s, &co);
    float2 v = firstAxis ? in[n * 24 + c] : in[r * 24 + n];
    acc.x += v.x * co - v.y * s;
    acc.y += v.x * s + v.y * co;
  }
  out[t] = acc;
}

__global__ void spectrum_kernel(const float* __restrict__ sig, float2* __restrict__ spec) {
  __shared__ float2 b0[576];
  __shared__ float2 b1[576];
  int f = blockIdx.x;
  int t = threadIdx.x;
  int r = t / 24, c = t % 24;
  b0[t] = make_float2(sig[f * 576 + t], 0.f);
  __syncthreads();
  dft24(b0, b1, t, -1.f, false); __syncthreads();
  dft24(b1, b0, t, -1.f, true);  __syncthreads();
  {
    int p2 = (r + 12) % 24 - 11;
    int q2 = (c + 12) % 24 - 11;
    float rr = (float)(1 + p2 * p2 + q2 * q2) * 5.f;
    float2 v = b0[t];
    b0[t] = make_float2(v.x / rr, v.y / rr);
  }
  __syncthreads();
  dft24(b0, b1, t, +1.f, false); __syncthreads();
  dft24(b1, b0, t, +1.f, true);  __syncthreads();
  {
    float winr = 0.5f * (1.f - cosf(TAU * (float)r / 24.f));
    float winc = 0.5f * (1.f - cosf(TAU * (float)c / 24.f));
    float w = winr * winc * (1.f / 576.f);
    float2 v = b0[t];
    b0[t] = make_float2(v.x * w, v.y * w);
  }
  __syncthreads();
  dft24(b0, b1, t, -1.f, false); __syncthreads();
  dft24(b1, b0, t, -1.f, true);  __syncthreads();
  int p = (r + 12) % 24, q = (c + 12) % 24;
  spec[f * 576 + p * 24 + q] = b0[t];
}

// ---------------- Stage 2: build split B and X0 = I + B/6 ----------------
__global__ void buildBX(const float2* __restrict__ spec, __hip_bfloat16* __restrict__ B,
                        __hip_bfloat16* __restrict__ X0, int c0, float scale) {
  int idx = blockIdx.x * 256 + threadIdx.x;   // 0..331775 (row*576+col, row<576)
  int cl = blockIdx.y;
  int c = c0 + cl;
  int row = idx / NK, col = idx % NK;
  int i = row / 24, j = row % 24, a = col / 24, b = col % 24;
  int u = 11 - i + a, v = 11 - j + b;
  float br = 0.f, bi = 0.f;
  if (u >= 0 && u < 24 && v >= 0 && v < 24) {
    float2 s0 = spec[(c * 2 + 0) * 576 + u * 24 + v];
    float2 s1 = spec[(c * 2 + 1) * 576 + u * 24 + v];
    float kx = (float)(a - 11), ky = (float)(b - 11);
    float xr = s0.x * kx + s1.x * ky;
    float xi = s0.y * kx + s1.y * ky;
    br = xi * scale;
    bi = -xr * scale;
  }
  size_t off = (size_t)cl * SETSTR + idx;
  __hip_bfloat16 h, l;
  bsplit(br, h, l); B[off] = h; B[off + PLN] = l;
  bsplit(bi, h, l); B[off + 2 * PLN] = h; B[off + 3 * PLN] = l;
  float d = (row == col) ? 1.f : 0.f;
  bsplit(br * (1.f / 6.f) + d, h, l); X0[off] = h; X0[off + PLN] = l;
  bsplit(bi * (1.f / 6.f), h, l);     X0[off + 2 * PLN] = h; X0[off + 3 * PLN] = l;
}

// ---------------- transpose the 4 split planes ----------------
__global__ __launch_bounds__(256) void transpose4(const __hip_bfloat16* __restrict__ src,
                                                  __hip_bfloat16* __restrict__ dst) {
  __shared__ __hip_bfloat16 tile[64][65];
  int cl = blockIdx.z;
  size_t off = (size_t)cl * SETSTR;
  int rB = blockIdx.y * 64, cB = blockIdx.x * 64;
  int tx = threadIdx.x & 63, ty = threadIdx.x >> 6;
  for (int p = 0; p < 4; ++p) {
    for (int li = 0; li < 16; ++li) {
      int r = ty * 16 + li;
      tile[r][tx] = src[off + (size_t)p * PLN + (size_t)(rB + r) * NK + cB + tx];
    }
    __syncthreads();
    for (int li = 0; li < 16; ++li) {
      int r = ty * 16 + li;
      dst[off + (size_t)p * PLN + (size_t)(cB + r) * NK + rB + tx] = tile[tx][r];
    }
    __syncthreads();
  }
}

// ---------------- Stage 3: batched split-complex MFMA GEMM, 128x128 tile ----------------
// D = alpha*(A*B) + delta*I.  A row-major [m][k] split planes; B given as BT [n][k].
// Writes D (row-major) and DT (transposed), split planes. Rows/cols >= 576 discarded.
__global__ __launch_bounds__(512, 2) void cgemm_mfma(
    const __hip_bfloat16* __restrict__ A, const __hip_bfloat16* __restrict__ BT,
    __hip_bfloat16* __restrict__ D, __hip_bfloat16* __restrict__ DT,
    float alpha, float delta) {
  __shared__ char lds[2][65536];   // A planes @0 (4*8192), B planes @32768
  const int t = threadIdx.x;
  const int lane = t & 63;
  const int wid = t >> 6;
  const int wm = wid >> 2, wn = wid & 3;          // 2 x 4 waves, wave tile 64x32
  const int cl = blockIdx.z;
  const int rowBase = blockIdx.y * 128, colBase = blockIdx.x * 128;
  const size_t chOff = (size_t)cl * SETSTR;
  const __hip_bfloat16* Ab = A + chOff;
  const __hip_bfloat16* Bb = BT + chOff;

  // staging: 2048 16B-chunks per operand; cid = i*512+t -> plane p, row r, phys chunk cp
  size_t gA[4], gB[4];
  int ldsOff[4];
#pragma unroll
  for (int i = 0; i < 4; ++i) {
    int cid = i * 512 + t;
    int p = cid >> 9, r = (cid >> 2) & 127, cp = cid & 3;
    int cg = cp ^ ((r >> 1) & 3);
    gA[i] = (size_t)p * PLN + (size_t)(rowBase + r) * NK + cg * 8;
    gB[i] = (size_t)p * PLN + (size_t)(colBase + r) * NK + cg * 8;
    ldsOff[i] = cid * 16;
  }
  // fragment read offsets
  int aoff[4], boff[2];
#pragma unroll
  for (int mi = 0; mi < 4; ++mi) {
    int ra = wm * 64 + mi * 16 + (lane & 15);
    int ch = (lane >> 4) ^ ((ra >> 1) & 3);
    aoff[mi] = (ra * 4 + ch) * 16;
  }
#pragma unroll
  for (int ni = 0; ni < 2; ++ni) {
    int cb = wn * 32 + ni * 16 + (lane & 15);
    int ch = (lane >> 4) ^ ((cb >> 1) & 3);
    boff[ni] = 32768 + (cb * 4 + ch) * 16;
  }

  f32x4 accP[4][2] = {}, accN[4][2] = {}, accI[4][2] = {};

  auto STAGE = [&](int buf, int k0) {
#pragma unroll
    for (int i = 0; i < 4; ++i) {
      gld16(Ab + gA[i] + k0, &lds[buf][ldsOff[i]]);
      gld16(Bb + gB[i] + k0, &lds[buf][32768 + ldsOff[i]]);
    }
  };

  STAGE(0, 0);
  __syncthreads();

  int cur = 0;
#pragma unroll 1
  for (int ks = 0; ks < 18; ++ks) {
    if (ks < 17) STAGE(cur ^ 1, (ks + 1) * 32);
    short8 arh[4], arl[4], aih[4], ail[4];
    short8 brh[2], brl[2], bih[2], bil[2];
#pragma unroll
    for (int mi = 0; mi < 4; ++mi) {
      const char* base = &lds[cur][aoff[mi]];
      arh[mi] = *(const short8*)(base);
      arl[mi] = *(const short8*)(base + 8192);
      aih[mi] = *(const short8*)(base + 16384);
      ail[mi] = *(const short8*)(base + 24576);
    }
#pragma unroll
    for (int ni = 0; ni < 2; ++ni) {
      const char* base = &lds[cur][boff[ni]];
      brh[ni] = *(const short8*)(base);
      brl[ni] = *(const short8*)(base + 8192);
      bih[ni] = *(const short8*)(base + 16384);
      bil[ni] = *(const short8*)(base + 24576);
    }
#pragma unroll
    for (int mi = 0; mi < 4; ++mi)
#pragma unroll
      for (int ni = 0; ni < 2; ++ni) {
        accP[mi][ni] = MFMA16(arh[mi], brh[ni], accP[mi][ni]);
        accP[mi][ni] = MFMA16(arh[mi], brl[ni], accP[mi][ni]);
        accP[mi][ni] = MFMA16(arl[mi], brh[ni], accP[mi][ni]);
        accN[mi][ni] = MFMA16(aih[mi], bih[ni], accN[mi][ni]);
        accN[mi][ni] = MFMA16(aih[mi], bil[ni], accN[mi][ni]);
        accN[mi][ni] = MFMA16(ail[mi], bih[ni], accN[mi][ni]);
        accI[mi][ni] = MFMA16(arh[mi], bih[ni], accI[mi][ni]);
        accI[mi][ni] = MFMA16(arh[mi], bil[ni], accI[mi][ni]);
        accI[mi][ni] = MFMA16(arl[mi], bih[ni], accI[mi][ni]);
        accI[mi][ni] = MFMA16(aih[mi], brh[ni], accI[mi][ni]);
        accI[mi][ni] = MFMA16(aih[mi], brl[ni], accI[mi][ni]);
        accI[mi][ni] = MFMA16(ail[mi], brh[ni], accI[mi][ni]);
      }
    __syncthreads();
    cur ^= 1;
  }

  __hip_bfloat16* Dp = D + chOff;
  __hip_bfloat16* Tp = DT + chOff;
#pragma unroll
  for (int mi = 0; mi < 4; ++mi)
#pragma unroll
    for (int ni = 0; ni < 2; ++ni) {
      int rb = rowBase + wm * 64 + mi * 16 + (lane >> 4) * 4;
      int cc = colBase + wn * 32 + ni * 16 + (lane & 15);
      if (cc >= NK) continue;
#pragma unroll
      for (int j = 0; j < 4; ++j) {
        int r = rb + j;
        if (r >= NK) continue;
        float vR = alpha * (accP[mi][ni][j] - accN[mi][ni][j]) + ((r == cc) ? delta : 0.f);
        float vI = alpha * accI[mi][ni][j];
        __hip_bfloat16 h, l;
        bsplit(vR, h, l);
        Dp[(size_t)r * NK + cc] = h;
        Dp[PLN + (size_t)r * NK + cc] = l;
        Tp[(size_t)cc * NK + r] = h;
        Tp[PLN + (size_t)cc * NK + r] = l;
        bsplit(vI, h, l);
        Dp[2 * PLN + (size_t)r * NK + cc] = h;
        Dp[3 * PLN + (size_t)r * NK + cc] = l;
        Tp[2 * PLN + (size_t)cc * NK + r] = h;
        Tp[3 * PLN + (size_t)cc * NK + r] = l;
      }
    }
}

// ---------------- Stage 4: slice + roll + separable DFTs ----------------
__global__ void passA(const __hip_bfloat16* __restrict__ X, float2* __restrict__ P) {
  int cl = blockIdx.y;
  int idx = blockIdx.x * 256 + threadIdx.x;
  int v = idx % 20, u = (idx / 20) % 20, q = (idx / 400) % 16, p = idx / 6400;
  int pp = (p + 7) % 16;
  int qq = (q + 7) % 16;
  int row = (pp + 5) * 24 + (qq + 5);
  int uu = (u + 9) % 20;
  int aa = uu + 3;
  const __hip_bfloat16* tb = X + (size_t)cl * SETSTR;
  float2 acc = make_float2(0.f, 0.f);
  for (int vp = 0; vp < 20; ++vp) {
    int vv = (vp + 9) % 20;
    int col = aa * 24 + (vv + 3);
    size_t o = (size_t)row * NK + col;
    float xr = __bfloat162float(tb[o]) + __bfloat162float(tb[PLN + o]);
    float xi = __bfloat162float(tb[2 * PLN + o]) + __bfloat162float(tb[3 * PLN + o]);
    float ang = (TAU / 20.f) * (float)((v * vp) % 20);
    float s, co;
    sincosf(ang, &s, &co);
    acc.x += xr * co - xi * s;
    acc.y += xr * s + xi * co;
  }
  P[(size_t)cl * MAPSZ + idx] = acc;
}

__global__ void passB(const float2* __restrict__ Pin, float2* __restrict__ Pout) {
  int cl = blockIdx.y;
  int idx = blockIdx.x * 256 + threadIdx.x;
  int v = idx % 20, u = (idx / 20) % 20, q = (idx / 400) % 16, p = idx / 6400;
  const float2* in = Pin + (size_t)cl * MAPSZ;
  float2 acc = make_float2(0.f, 0.f);
  for (int up = 0; up < 20; ++up) {
    float2 val = in[(p * 16 + q) * 400 + up * 20 + v];
    float ang = (TAU / 20.f) * (float)((u * up) % 20);
    float s, co;
    sincosf(ang, &s, &co);
    acc.x += val.x * co - val.y * s;
    acc.y += val.x * s + val.y * co;
  }
  Pout[(size_t)cl * MAPSZ + idx] = acc;
}

__global__ void passC(const float2* __restrict__ Pin, float2* __restrict__ Pout) {
  int cl = blockIdx.y;
  int idx = blockIdx.x * 256 + threadIdx.x;
  int v = idx % 20, u = (idx / 20) % 20, q = (idx / 400) % 16, p = idx / 6400;
  const float2* in = Pin + (size_t)cl * MAPSZ;
  float2 acc = make_float2(0.f, 0.f);
  for (int qp = 0; qp < 16; ++qp) {
    float2 val = in[(p * 16 + qp) * 400 + u * 20 + v];
    float ang = -(TAU / 16.f) * (float)((q * qp) % 16);
    float s, co;
    sincosf(ang, &s, &co);
    acc.x += val.x * co - val.y * s;
    acc.y += val.x * s + val.y * co;
  }
  Pout[(size_t)cl * MAPSZ + idx] = acc;
}

// passD: final DFT, write split-bf16 m directly into padded [n][KOUT] planes
__global__ void passD(const float2* __restrict__ Pin, __hip_bfloat16* __restrict__ ms, int c0) {
  int cl = blockIdx.y;
  int c = c0 + cl;
  int idx = blockIdx.x * 256 + threadIdx.x;
  int v = idx % 20, u = (idx / 20) % 20, q = (idx / 400) % 16, p = idx / 6400;
  const float2* in = Pin + (size_t)cl * MAPSZ;
  float acc = 0.f;
  for (int pp = 0; pp < 16; ++pp) {
    float2 val = in[(pp * 16 + q) * 400 + u * 20 + v];
    float ang = -(TAU / 16.f) * (float)((p * pp) % 16);
    float s, co;
    sincosf(ang, &s, &co);
    acc += val.x * co - val.y * s;
  }
  acc *= (1.f / 400.f);
  int n = c * 256 + idx / 400;          // o = p*16+q
  int k = idx % 400;                    // k = u*20+v
  __hip_bfloat16 h, l;
  bsplit(acc, h, l);
  ms[(size_t)n * KOUT + k] = h;
  ms[MPL + (size_t)n * KOUT + k] = l;
}

// zero the k in [400,416) pad of the m planes
__global__ void pad_m(__hip_bfloat16* __restrict__ ms) {
  int idx = blockIdx.x * 256 + threadIdx.x;   // 4096*16*2
  int p = idx >> 16;
  int rem = idx & 65535;
  int n = rem >> 4;
  int k = 400 + (rem & 15);
  ms[(size_t)p * MPL + (size_t)n * KOUT + k] = __float2bfloat16(0.f);
}

// convert x (8192x400 f32) to split bf16 padded [2][8192][KOUT]
__global__ void prep_x(const float* __restrict__ x, __hip_bfloat16* __restrict__ xs) {
  int idx = blockIdx.x * 256 + threadIdx.x;   // 8192*52
  if (idx >= 8192 * 52) return;
  int b = idx / 52, c8 = idx % 52;
  int k = c8 * 8;
  short8 hh = {}, ll = {};
  if (k < 400) {
    const float4* xp = (const float4*)(x + (size_t)b * 400 + k);
    float4 v0 = xp[0], v1 = xp[1];
    float vals[8] = {v0.x, v0.y, v0.z, v0.w, v1.x, v1.y, v1.z, v1.w};
#pragma unroll
    for (int i = 0; i < 8; ++i) {
      __hip_bfloat16 h, l;
      bsplit(vals[i], h, l);
      hh[i] = braw(h);
      ll[i] = braw(l);
    }
  }
  *(short8*)(xs + (size_t)b * KOUT + k) = hh;
  *(short8*)(xs + XPL + (size_t)b * KOUT + k) = ll;
}

// ---------------- Stage 5: output GEMM, split-bf16 MFMA, 128x128 tile ----------------
// Y[b][n] = sum_k X[b][k]*M[n][k];  A = xs [2][8192][KOUT], B = ms [2][4096][KOUT]
__global__ __launch_bounds__(512, 2) void out_mfma(
    const __hip_bfloat16* __restrict__ xs, const __hip_bfloat16* __restrict__ ms,
    float* __restrict__ Y) {
  __shared__ char lds[2][32768];   // A planes @0 (2*8192), B planes @16384
  const int t = threadIdx.x;
  const int lane = t & 63;
  const int wid = t >> 6;
  const int wm = wid >> 2, wn = wid & 3;
  const int rowBase = blockIdx.y * 128, colBase = blockIdx.x * 128;

  size_t gA[2], gB[2];
  int ldsOff[2];
#pragma unroll
  for (int i = 0; i < 2; ++i) {
    int cid = i * 512 + t;
    int p = cid >> 9, r = (cid >> 2) & 127, cp = cid & 3;
    int cg = cp ^ ((r >> 1) & 3);
    gA[i] = (size_t)p * XPL + (size_t)(rowBase + r) * KOUT + cg * 8;
    gB[i] = (size_t)p * MPL + (size_t)(colBase + r) * KOUT + cg * 8;
    ldsOff[i] = cid * 16;
  }
  int aoff[4], boff[2];
#pragma unroll
  for (int mi = 0; mi < 4; ++mi) {
    int ra = wm * 64 + mi * 16 + (lane & 15);
    int ch = (lane >> 4) ^ ((ra >> 1) & 3);
    aoff[mi] = (ra * 4 + ch) * 16;
  }
#pragma unroll
  for (int ni = 0; ni < 2; ++ni) {
    int cb = wn * 32 + ni * 16 + (lane & 15);
    int ch = (lane >> 4) ^ ((cb >> 1) & 3);
    boff[ni] = 16384 + (cb * 4 + ch) * 16;
  }

  f32x4 acc[4][2] = {};

  auto STAGE = [&](int buf, int k0) {
#pragma unroll
    for (int i = 0; i < 2; ++i) {
      gld16(xs + gA[i] + k0, &lds[buf][ldsOff[i]]);
      gld16(ms + gB[i] + k0, &lds[buf][16384 + ldsOff[i]]);
    }
  };

  STAGE(0, 0);
  __syncthreads();

  int cur = 0;
#pragma unroll 1
  for (int ks = 0; ks < 13; ++ks) {
    if (ks < 12) STAGE(cur ^ 1, (ks + 1) * 32);
    short8 ah[4], al[4], bh[2], bl[2];
#pragma unroll
    for (int mi = 0; mi < 4; ++mi) {
      const char* base = &lds[cur][aoff[mi]];
      ah[mi] = *(const short8*)(base);
      al[mi] = *(const short8*)(base + 8192);
    }
#pragma unroll
    for (int ni = 0; ni < 2; ++ni) {
      const char* base = &lds[cur][boff[ni]];
      bh[ni] = *(const short8*)(base);
      bl[ni] = *(const short8*)(base + 8192);
    }
#pragma unroll
    for (int mi = 0; mi < 4; ++mi)
#pragma unroll
      for (int ni = 0; ni < 2; ++ni) {
        acc[mi][ni] = MFMA16(ah[mi], bh[ni], acc[mi][ni]);
        acc[mi][ni] = MFMA16(ah[mi], bl[ni], acc[mi][ni]);
        acc[mi][ni] = MFMA16(al[mi], bh[ni], acc[mi][ni]);
      }
    __syncthreads();
    cur ^= 1;
  }

#pragma unroll
  for (int mi = 0; mi < 4; ++mi)
#pragma unroll
    for (int ni = 0; ni < 2; ++ni) {
      int rb = rowBase + wm * 64 + mi * 16 + (lane >> 4) * 4;
      int cc = colBase + wn * 32 + ni * 16 + (lane & 15);
#pragma unroll
      for (int j = 0; j < 4; ++j)
        Y[(size_t)(rb + j) * 4096 + cc] = acc[mi][ni][j];
    }
}

// ---------------- Launcher ----------------
extern "C" void kernel_launch(void* const* d_in, const int* in_sizes, int n_in,
                              void* d_out, int out_size, void* d_ws, size_t ws_size,
                              hipStream_t stream) {
  const float* x = (const float*)d_in[0];     // (8192,1,20,20)
  const float* sig = (const float*)d_in[1];   // (16,2,24,24)
  float* out = (float*)d_out;                 // (8192,16,16,16)
  char* ws = (char*)d_ws;

  const size_t specBytes = 32ull * 576 * sizeof(float2);
  const size_t xsBytes = 2ull * XPL * 2;
  const size_t msBytes = 2ull * MPL * 2;
  const size_t fixed = specBytes + xsBytes + msBytes;
  const size_t setB = SETSTR * 2;                       // bytes per split set
  const size_t perCh = 6 * setB + 2ull * MAPSZ * 8;

  int cg = 1;
  if (ws_size > fixed) {
    size_t av = (ws_size - fixed) / perCh;
    cg = (av < 1) ? 1 : (av > 16 ? 16 : (int)av);
  }

  float2* spec = (float2*)ws;
  __hip_bfloat16* xs = (__hip_bfloat16*)(ws + specBytes);
  __hip_bfloat16* ms = (__hip_bfloat16*)(ws + specBytes + xsBytes);
  __hip_bfloat16* Bst = (__hip_bfloat16*)(ws + fixed);
  __hip_bfloat16* BTst = Bst + (size_t)cg * SETSTR;
  __hip_bfloat16* X0 = BTst + (size_t)cg * SETSTR;
  __hip_bfloat16* X0T = X0 + (size_t)cg * SETSTR;
  __hip_bfloat16* X1 = X0T + (size_t)cg * SETSTR;
  __hip_bfloat16* X1T = X1 + (size_t)cg * SETSTR;
  float2* P0 = (float2*)(X1T + (size_t)cg * SETSTR);
  float2* P1 = P0 + (size_t)cg * MAPSZ;

  spectrum_kernel<<<dim3(32), dim3(576), 0, stream>>>(sig, spec);
  prep_x<<<dim3((8192 * 52 + 255) / 256), dim3(256), 0, stream>>>(x, xs);
  pad_m<<<dim3(512), dim3(256), 0, stream>>>(ms);

  const float scale = 1.f / 256.f;  // s = 8 squarings
  for (int c0 = 0; c0 < 16; c0 += cg) {
    int g = (16 - c0 < cg) ? (16 - c0) : cg;
    buildBX<<<dim3(1296, g), dim3(256), 0, stream>>>(spec, Bst, X0, c0, scale);
    transpose4<<<dim3(9, 9, g), dim3(256), 0, stream>>>(Bst, BTst);
    transpose4<<<dim3(9, 9, g), dim3(256), 0, stream>>>(X0, X0T);
    __hip_bfloat16 *xr = X0, *xt = X0T, *yr = X1, *yt = X1T;
    for (int k = 5; k >= 1; --k) {
      cgemm_mfma<<<dim3(5, 5, g), dim3(512), 0, stream>>>(Bst, xt, yr, yt, 1.f / (float)k, 1.f);
      __hip_bfloat16* tmp;
      tmp = xr; xr = yr; yr = tmp;
      tmp = xt; xt = yt; yt = tmp;
    }
    for (int t8 = 0; t8 < 8; ++t8) {
      cgemm_mfma<<<dim3(5, 5, g), dim3(512), 0, stream>>>(xr, xt, yr, yt, 1.f, 0.f);
      __hip_bfloat16* tmp;
      tmp = xr; xr = yr; yr = tmp;
      tmp = xt; xt = yt; yt = tmp;
    }
    passA<<<dim3(400, g), dim3(256), 0, stream>>>(xr, P0);
    passB<<<dim3(400, g), dim3(256), 0, stream>>>(P0, P1);
    passC<<<dim3(400, g), dim3(256), 0, stream>>>(P1, P0);
    passD<<<dim3(400, g), dim3(256), 0, stream>>>(P0, ms, c0);
  }

  out_mfma<<<dim3(32, 64), dim3(512), 0, stream>>>(xs, ms, out);
}

// Round 4
// 1858.938 us; speedup vs baseline: 8.6068x; 1.3143x over previous
//
#include <hip/hip_runtime.h>
#include <hip/hip_bf16.h>
#include <math.h>

#define TAU 6.283185307179586f
#define NK 576                    // matrix dimension (K always exact: 18*32)
#define NPAD 640                  // padded row count for 128-row tiles
#define PLN ((size_t)NPAD * NK)   // elems per padded plane = 368640
#define SETSTR ((size_t)4 * PLN)  // elems per 4-plane split set
#define MAPSZ 102400              // 16*16*20*20
#define KOUT 416                  // padded K for output gemm (13*32)
#define XPL ((size_t)8192 * KOUT)
#define MPL ((size_t)4096 * KOUT)

typedef __attribute__((ext_vector_type(8))) short short8;
typedef __attribute__((ext_vector_type(4))) float f32x4;

__device__ inline void bsplit(float v, __hip_bfloat16& h, __hip_bfloat16& l) {
  h = __float2bfloat16(v);
  l = __float2bfloat16(v - __bfloat162float(h));
}
__device__ inline short braw(__hip_bfloat16 b) { return *reinterpret_cast<short*>(&b); }

__device__ inline void gld16(const void* g, const void* l) {
  __builtin_amdgcn_global_load_lds((const __attribute__((address_space(1))) unsigned*)g,
                                   (__attribute__((address_space(3))) unsigned*)l, 16, 0, 0);
}

#define MFMA16(a, b, c) __builtin_amdgcn_mfma_f32_16x16x32_bf16(a, b, c, 0, 0, 0)

// ---------------- Stage 1: signal -> spectrum ----------------
__device__ inline void dft24(const float2* in, float2* out, int t, float sgn, bool firstAxis) {
  int r = t / 24, c = t % 24;
  int kk = firstAxis ? r : c;
  float2 acc = make_float2(0.f, 0.f);
  for (int n = 0; n < 24; ++n) {
    float ang = sgn * (TAU / 24.f) * (float)((kk * n) % 24);
    float s, co;
    sincosf(ang, &s, &co);
    float2 v = firstAxis ? in[n * 24 + c] : in[r * 24 + n];
    acc.x += v.x * co - v.y * s;
    acc.y += v.x * s + v.y * co;
  }
  out[t] = acc;
}

__global__ void spectrum_kernel(const float* __restrict__ sig, float2* __restrict__ spec) {
  __shared__ float2 b0[576];
  __shared__ float2 b1[576];
  int f = blockIdx.x;
  int t = threadIdx.x;
  int r = t / 24, c = t % 24;
  b0[t] = make_float2(sig[f * 576 + t], 0.f);
  __syncthreads();
  dft24(b0, b1, t, -1.f, false); __syncthreads();
  dft24(b1, b0, t, -1.f, true);  __syncthreads();
  {
    int p2 = (r + 12) % 24 - 11;
    int q2 = (c + 12) % 24 - 11;
    float rr = (float)(1 + p2 * p2 + q2 * q2) * 5.f;
    float2 v = b0[t];
    b0[t] = make_float2(v.x / rr, v.y / rr);
  }
  __syncthreads();
  dft24(b0, b1, t, +1.f, false); __syncthreads();
  dft24(b1, b0, t, +1.f, true);  __syncthreads();
  {
    float winr = 0.5f * (1.f - cosf(TAU * (float)r / 24.f));
    float winc = 0.5f * (1.f - cosf(TAU * (float)c / 24.f));
    float w = winr * winc * (1.f / 576.f);
    float2 v = b0[t];
    b0[t] = make_float2(v.x * w, v.y * w);
  }
  __syncthreads();
  dft24(b0, b1, t, -1.f, false); __syncthreads();
  dft24(b1, b0, t, -1.f, true);  __syncthreads();
  int p = (r + 12) % 24, q = (c + 12) % 24;
  spec[f * 576 + p * 24 + q] = b0[t];
}

// ---------------- Stage 2: build split B and X0 = I + B/5 ----------------
__global__ void buildBX(const float2* __restrict__ spec, __hip_bfloat16* __restrict__ B,
                        __hip_bfloat16* __restrict__ X0, int c0, float scale) {
  int idx = blockIdx.x * 256 + threadIdx.x;   // 0..331775 (row*576+col, row<576)
  int cl = blockIdx.y;
  int c = c0 + cl;
  int row = idx / NK, col = idx % NK;
  int i = row / 24, j = row % 24, a = col / 24, b = col % 24;
  int u = 11 - i + a, v = 11 - j + b;
  float br = 0.f, bi = 0.f;
  if (u >= 0 && u < 24 && v >= 0 && v < 24) {
    float2 s0 = spec[(c * 2 + 0) * 576 + u * 24 + v];
    float2 s1 = spec[(c * 2 + 1) * 576 + u * 24 + v];
    float kx = (float)(a - 11), ky = (float)(b - 11);
    float xr = s0.x * kx + s1.x * ky;
    float xi = s0.y * kx + s1.y * ky;
    br = xi * scale;
    bi = -xr * scale;
  }
  size_t off = (size_t)cl * SETSTR + idx;
  __hip_bfloat16 h, l;
  bsplit(br, h, l); B[off] = h; B[off + PLN] = l;
  bsplit(bi, h, l); B[off + 2 * PLN] = h; B[off + 3 * PLN] = l;
  float d = (row == col) ? 1.f : 0.f;
  bsplit(br * (1.f / 5.f) + d, h, l); X0[off] = h; X0[off + PLN] = l;
  bsplit(bi * (1.f / 5.f), h, l);     X0[off + 2 * PLN] = h; X0[off + 3 * PLN] = l;
}

// ---------------- transpose the 4 split planes ----------------
__global__ __launch_bounds__(256) void transpose4(const __hip_bfloat16* __restrict__ src,
                                                  __hip_bfloat16* __restrict__ dst) {
  __shared__ __hip_bfloat16 tile[64][65];
  int cl = blockIdx.z;
  size_t off = (size_t)cl * SETSTR;
  int rB = blockIdx.y * 64, cB = blockIdx.x * 64;
  int tx = threadIdx.x & 63, ty = threadIdx.x >> 6;
  for (int p = 0; p < 4; ++p) {
    for (int li = 0; li < 16; ++li) {
      int r = ty * 16 + li;
      tile[r][tx] = src[off + (size_t)p * PLN + (size_t)(rB + r) * NK + cB + tx];
    }
    __syncthreads();
    for (int li = 0; li < 16; ++li) {
      int r = ty * 16 + li;
      dst[off + (size_t)p * PLN + (size_t)(cB + r) * NK + rB + tx] = tile[tx][r];
    }
    __syncthreads();
  }
}

// ---------------- Stage 3: batched split-complex MFMA GEMM, 128x128 tile ----------------
// D = alpha*(A*B) + delta*I.  A row-major [m][k] split planes; B given as BT [n][k].
// wf bit0: write D (row-major); bit1: write DT (transposed).
// Flat 1D grid of 25*g blocks; when g==16, channel c -> XCD c&7 (L2 locality).
__global__ __launch_bounds__(512, 2) void cgemm_mfma(
    const __hip_bfloat16* __restrict__ A, const __hip_bfloat16* __restrict__ BT,
    __hip_bfloat16* __restrict__ D, __hip_bfloat16* __restrict__ DT,
    float alpha, float delta, int wf) {
  __shared__ char lds[2][65536];   // A planes @0 (4*8192), B planes @32768
  const int t = threadIdx.x;
  const int lane = t & 63;
  const int wid = t >> 6;
  const int wm = wid >> 2, wn = wid & 3;          // 2 x 4 waves, wave tile 64x32
  // block remap: XCD-local channels when full 16-channel group
  int p0 = blockIdx.x;
  int cl, tile;
  if (gridDim.x == 400) {
    cl = (p0 & 7) + ((p0 >> 3) / 25) * 8;
    tile = (p0 >> 3) % 25;
  } else {
    cl = p0 / 25;
    tile = p0 % 25;
  }
  const int rowBase = (tile / 5) * 128, colBase = (tile % 5) * 128;
  const size_t chOff = (size_t)cl * SETSTR;
  const __hip_bfloat16* Ab = A + chOff;
  const __hip_bfloat16* Bb = BT + chOff;

  // staging: 2048 16B-chunks per operand; cid = i*512+t -> plane p, row r, phys chunk cp
  size_t gA[4], gB[4];
  int ldsOff[4];
#pragma unroll
  for (int i = 0; i < 4; ++i) {
    int cid = i * 512 + t;
    int pp = cid >> 9, r = (cid >> 2) & 127, cp = cid & 3;
    int cg = cp ^ ((r >> 1) & 3);
    gA[i] = (size_t)pp * PLN + (size_t)(rowBase + r) * NK + cg * 8;
    gB[i] = (size_t)pp * PLN + (size_t)(colBase + r) * NK + cg * 8;
    ldsOff[i] = cid * 16;
  }
  // fragment read offsets
  int aoff[4], boff[2];
#pragma unroll
  for (int mi = 0; mi < 4; ++mi) {
    int ra = wm * 64 + mi * 16 + (lane & 15);
    int ch = (lane >> 4) ^ ((ra >> 1) & 3);
    aoff[mi] = (ra * 4 + ch) * 16;
  }
#pragma unroll
  for (int ni = 0; ni < 2; ++ni) {
    int cb = wn * 32 + ni * 16 + (lane & 15);
    int ch = (lane >> 4) ^ ((cb >> 1) & 3);
    boff[ni] = 32768 + (cb * 4 + ch) * 16;
  }

  f32x4 accP[4][2] = {}, accN[4][2] = {}, accI[4][2] = {};

  auto STAGE = [&](int buf, int k0) {
#pragma unroll
    for (int i = 0; i < 4; ++i) {
      gld16(Ab + gA[i] + k0, &lds[buf][ldsOff[i]]);
      gld16(Bb + gB[i] + k0, &lds[buf][32768 + ldsOff[i]]);
    }
  };

  STAGE(0, 0);
  __syncthreads();

  int cur = 0;
#pragma unroll 1
  for (int ks = 0; ks < 18; ++ks) {
    if (ks < 17) STAGE(cur ^ 1, (ks + 1) * 32);
    short8 arh[4], arl[4], aih[4], ail[4];
    short8 brh[2], brl[2], bih[2], bil[2];
#pragma unroll
    for (int mi = 0; mi < 4; ++mi) {
      const char* base = &lds[cur][aoff[mi]];
      arh[mi] = *(const short8*)(base);
      arl[mi] = *(const short8*)(base + 8192);
      aih[mi] = *(const short8*)(base + 16384);
      ail[mi] = *(const short8*)(base + 24576);
    }
#pragma unroll
    for (int ni = 0; ni < 2; ++ni) {
      const char* base = &lds[cur][boff[ni]];
      brh[ni] = *(const short8*)(base);
      brl[ni] = *(const short8*)(base + 8192);
      bih[ni] = *(const short8*)(base + 16384);
      bil[ni] = *(const short8*)(base + 24576);
    }
#pragma unroll
    for (int mi = 0; mi < 4; ++mi)
#pragma unroll
      for (int ni = 0; ni < 2; ++ni) {
        accP[mi][ni] = MFMA16(arh[mi], brh[ni], accP[mi][ni]);
        accP[mi][ni] = MFMA16(arh[mi], brl[ni], accP[mi][ni]);
        accP[mi][ni] = MFMA16(arl[mi], brh[ni], accP[mi][ni]);
        accN[mi][ni] = MFMA16(aih[mi], bih[ni], accN[mi][ni]);
        accN[mi][ni] = MFMA16(aih[mi], bil[ni], accN[mi][ni]);
        accN[mi][ni] = MFMA16(ail[mi], bih[ni], accN[mi][ni]);
        accI[mi][ni] = MFMA16(arh[mi], bih[ni], accI[mi][ni]);
        accI[mi][ni] = MFMA16(arh[mi], bil[ni], accI[mi][ni]);
        accI[mi][ni] = MFMA16(arl[mi], bih[ni], accI[mi][ni]);
        accI[mi][ni] = MFMA16(aih[mi], brh[ni], accI[mi][ni]);
        accI[mi][ni] = MFMA16(aih[mi], brl[ni], accI[mi][ni]);
        accI[mi][ni] = MFMA16(ail[mi], brh[ni], accI[mi][ni]);
      }
    __syncthreads();
    cur ^= 1;
  }

  __hip_bfloat16* Dp = D + chOff;
  __hip_bfloat16* Tp = DT + chOff;
#pragma unroll
  for (int mi = 0; mi < 4; ++mi)
#pragma unroll
    for (int ni = 0; ni < 2; ++ni) {
      int rb = rowBase + wm * 64 + mi * 16 + (lane >> 4) * 4;
      int cc = colBase + wn * 32 + ni * 16 + (lane & 15);
      if (cc >= NK) continue;
#pragma unroll
      for (int j = 0; j < 4; ++j) {
        int r = rb + j;
        if (r >= NK) continue;
        float vR = alpha * (accP[mi][ni][j] - accN[mi][ni][j]) + ((r == cc) ? delta : 0.f);
        float vI = alpha * accI[mi][ni][j];
        __hip_bfloat16 hR, lR, hI, lI;
        bsplit(vR, hR, lR);
        bsplit(vI, hI, lI);
        if (wf & 1) {
          Dp[(size_t)r * NK + cc] = hR;
          Dp[PLN + (size_t)r * NK + cc] = lR;
          Dp[2 * PLN + (size_t)r * NK + cc] = hI;
          Dp[3 * PLN + (size_t)r * NK + cc] = lI;
        }
        if (wf & 2) {
          Tp[(size_t)cc * NK + r] = hR;
          Tp[PLN + (size_t)cc * NK + r] = lR;
          Tp[2 * PLN + (size_t)cc * NK + r] = hI;
          Tp[3 * PLN + (size_t)cc * NK + r] = lI;
        }
      }
    }
}

// ---------------- Stage 4: slice + roll + separable DFTs ----------------
__global__ void passA(const __hip_bfloat16* __restrict__ X, float2* __restrict__ P) {
  int cl = blockIdx.y;
  int idx = blockIdx.x * 256 + threadIdx.x;
  int v = idx % 20, u = (idx / 20) % 20, q = (idx / 400) % 16, p = idx / 6400;
  int pp = (p + 7) % 16;
  int qq = (q + 7) % 16;
  int row = (pp + 5) * 24 + (qq + 5);
  int uu = (u + 9) % 20;
  int aa = uu + 3;
  const __hip_bfloat16* tb = X + (size_t)cl * SETSTR;
  float2 acc = make_float2(0.f, 0.f);
  for (int vp = 0; vp < 20; ++vp) {
    int vv = (vp + 9) % 20;
    int col = aa * 24 + (vv + 3);
    size_t o = (size_t)row * NK + col;
    float xr = __bfloat162float(tb[o]) + __bfloat162float(tb[PLN + o]);
    float xi = __bfloat162float(tb[2 * PLN + o]) + __bfloat162float(tb[3 * PLN + o]);
    float ang = (TAU / 20.f) * (float)((v * vp) % 20);
    float s, co;
    sincosf(ang, &s, &co);
    acc.x += xr * co - xi * s;
    acc.y += xr * s + xi * co;
  }
  P[(size_t)cl * MAPSZ + idx] = acc;
}

__global__ void passB(const float2* __restrict__ Pin, float2* __restrict__ Pout) {
  int cl = blockIdx.y;
  int idx = blockIdx.x * 256 + threadIdx.x;
  int v = idx % 20, u = (idx / 20) % 20, q = (idx / 400) % 16, p = idx / 6400;
  const float2* in = Pin + (size_t)cl * MAPSZ;
  float2 acc = make_float2(0.f, 0.f);
  for (int up = 0; up < 20; ++up) {
    float2 val = in[(p * 16 + q) * 400 + up * 20 + v];
    float ang = (TAU / 20.f) * (float)((u * up) % 20);
    float s, co;
    sincosf(ang, &s, &co);
    acc.x += val.x * co - val.y * s;
    acc.y += val.x * s + val.y * co;
  }
  Pout[(size_t)cl * MAPSZ + idx] = acc;
}

__global__ void passC(const float2* __restrict__ Pin, float2* __restrict__ Pout) {
  int cl = blockIdx.y;
  int idx = blockIdx.x * 256 + threadIdx.x;
  int v = idx % 20, u = (idx / 20) % 20, q = (idx / 400) % 16, p = idx / 6400;
  const float2* in = Pin + (size_t)cl * MAPSZ;
  float2 acc = make_float2(0.f, 0.f);
  for (int qp = 0; qp < 16; ++qp) {
    float2 val = in[(p * 16 + qp) * 400 + u * 20 + v];
    float ang = -(TAU / 16.f) * (float)((q * qp) % 16);
    float s, co;
    sincosf(ang, &s, &co);
    acc.x += val.x * co - val.y * s;
    acc.y += val.x * s + val.y * co;
  }
  Pout[(size_t)cl * MAPSZ + idx] = acc;
}

// passD: final DFT, write split-bf16 m directly into padded [n][KOUT] planes
__global__ void passD(const float2* __restrict__ Pin, __hip_bfloat16* __restrict__ ms, int c0) {
  int cl = blockIdx.y;
  int c = c0 + cl;
  int idx = blockIdx.x * 256 + threadIdx.x;
  int v = idx % 20, u = (idx / 20) % 20, q = (idx / 400) % 16, p = idx / 6400;
  const float2* in = Pin + (size_t)cl * MAPSZ;
  float acc = 0.f;
  for (int pp = 0; pp < 16; ++pp) {
    float2 val = in[(pp * 16 + q) * 400 + u * 20 + v];
    float ang = -(TAU / 16.f) * (float)((p * pp) % 16);
    float s, co;
    sincosf(ang, &s, &co);
    acc += val.x * co - val.y * s;
  }
  acc *= (1.f / 400.f);
  int n = c * 256 + idx / 400;          // o = p*16+q
  int k = idx % 400;                    // k = u*20+v
  __hip_bfloat16 h, l;
  bsplit(acc, h, l);
  ms[(size_t)n * KOUT + k] = h;
  ms[MPL + (size_t)n * KOUT + k] = l;
}

// zero the k in [400,416) pad of the m planes
__global__ void pad_m(__hip_bfloat16* __restrict__ ms) {
  int idx = blockIdx.x * 256 + threadIdx.x;   // 4096*16*2
  int p = idx >> 16;
  int rem = idx & 65535;
  int n = rem >> 4;
  int k = 400 + (rem & 15);
  ms[(size_t)p * MPL + (size_t)n * KOUT + k] = __float2bfloat16(0.f);
}

// convert x (8192x400 f32) to split bf16 padded [2][8192][KOUT]
__global__ void prep_x(const float* __restrict__ x, __hip_bfloat16* __restrict__ xs) {
  int idx = blockIdx.x * 256 + threadIdx.x;   // 8192*52
  if (idx >= 8192 * 52) return;
  int b = idx / 52, c8 = idx % 52;
  int k = c8 * 8;
  short8 hh = {}, ll = {};
  if (k < 400) {
    const float4* xp = (const float4*)(x + (size_t)b * 400 + k);
    float4 v0 = xp[0], v1 = xp[1];
    float vals[8] = {v0.x, v0.y, v0.z, v0.w, v1.x, v1.y, v1.z, v1.w};
#pragma unroll
    for (int i = 0; i < 8; ++i) {
      __hip_bfloat16 h, l;
      bsplit(vals[i], h, l);
      hh[i] = braw(h);
      ll[i] = braw(l);
    }
  }
  *(short8*)(xs + (size_t)b * KOUT + k) = hh;
  *(short8*)(xs + XPL + (size_t)b * KOUT + k) = ll;
}

// ---------------- Stage 5: output GEMM, split-bf16 MFMA, 128x128 tile ----------------
__global__ __launch_bounds__(512, 2) void out_mfma(
    const __hip_bfloat16* __restrict__ xs, const __hip_bfloat16* __restrict__ ms,
    float* __restrict__ Y) {
  __shared__ char lds[2][32768];   // A planes @0 (2*8192), B planes @16384
  const int t = threadIdx.x;
  const int lane = t & 63;
  const int wid = t >> 6;
  const int wm = wid >> 2, wn = wid & 3;
  const int rowBase = blockIdx.y * 128, colBase = blockIdx.x * 128;

  size_t gA[2], gB[2];
  int ldsOff[2];
#pragma unroll
  for (int i = 0; i < 2; ++i) {
    int cid = i * 512 + t;
    int p = cid >> 9, r = (cid >> 2) & 127, cp = cid & 3;
    int cg = cp ^ ((r >> 1) & 3);
    gA[i] = (size_t)p * XPL + (size_t)(rowBase + r) * KOUT + cg * 8;
    gB[i] = (size_t)p * MPL + (size_t)(colBase + r) * KOUT + cg * 8;
    ldsOff[i] = cid * 16;
  }
  int aoff[4], boff[2];
#pragma unroll
  for (int mi = 0; mi < 4; ++mi) {
    int ra = wm * 64 + mi * 16 + (lane & 15);
    int ch = (lane >> 4) ^ ((ra >> 1) & 3);
    aoff[mi] = (ra * 4 + ch) * 16;
  }
#pragma unroll
  for (int ni = 0; ni < 2; ++ni) {
    int cb = wn * 32 + ni * 16 + (lane & 15);
    int ch = (lane >> 4) ^ ((cb >> 1) & 3);
    boff[ni] = 16384 + (cb * 4 + ch) * 16;
  }

  f32x4 acc[4][2] = {};

  auto STAGE = [&](int buf, int k0) {
#pragma unroll
    for (int i = 0; i < 2; ++i) {
      gld16(xs + gA[i] + k0, &lds[buf][ldsOff[i]]);
      gld16(ms + gB[i] + k0, &lds[buf][16384 + ldsOff[i]]);
    }
  };

  STAGE(0, 0);
  __syncthreads();

  int cur = 0;
#pragma unroll 1
  for (int ks = 0; ks < 13; ++ks) {
    if (ks < 12) STAGE(cur ^ 1, (ks + 1) * 32);
    short8 ah[4], al[4], bh[2], bl[2];
#pragma unroll
    for (int mi = 0; mi < 4; ++mi) {
      const char* base = &lds[cur][aoff[mi]];
      ah[mi] = *(const short8*)(base);
      al[mi] = *(const short8*)(base + 8192);
    }
#pragma unroll
    for (int ni = 0; ni < 2; ++ni) {
      const char* base = &lds[cur][boff[ni]];
      bh[ni] = *(const short8*)(base);
      bl[ni] = *(const short8*)(base + 8192);
    }
#pragma unroll
    for (int mi = 0; mi < 4; ++mi)
#pragma unroll
      for (int ni = 0; ni < 2; ++ni) {
        acc[mi][ni] = MFMA16(ah[mi], bh[ni], acc[mi][ni]);
        acc[mi][ni] = MFMA16(ah[mi], bl[ni], acc[mi][ni]);
        acc[mi][ni] = MFMA16(al[mi], bh[ni], acc[mi][ni]);
      }
    __syncthreads();
    cur ^= 1;
  }

#pragma unroll
  for (int mi = 0; mi < 4; ++mi)
#pragma unroll
    for (int ni = 0; ni < 2; ++ni) {
      int rb = rowBase + wm * 64 + mi * 16 + (lane >> 4) * 4;
      int cc = colBase + wn * 32 + ni * 16 + (lane & 15);
#pragma unroll
      for (int j = 0; j < 4; ++j)
        Y[(size_t)(rb + j) * 4096 + cc] = acc[mi][ni][j];
    }
}

// ---------------- Launcher ----------------
extern "C" void kernel_launch(void* const* d_in, const int* in_sizes, int n_in,
                              void* d_out, int out_size, void* d_ws, size_t ws_size,
                              hipStream_t stream) {
  const float* x = (const float*)d_in[0];     // (8192,1,20,20)
  const float* sig = (const float*)d_in[1];   // (16,2,24,24)
  float* out = (float*)d_out;                 // (8192,16,16,16)
  char* ws = (char*)d_ws;

  const size_t specBytes = 32ull * 576 * sizeof(float2);
  const size_t xsBytes = 2ull * XPL * 2;
  const size_t msBytes = 2ull * MPL * 2;
  const size_t fixed = specBytes + xsBytes + msBytes;
  const size_t setB = SETSTR * 2;                       // bytes per split set
  const size_t perCh = 5 * setB + 2ull * MAPSZ * 8;     // B, X0, X0T, X1, X1T + P0/P1

  int cg = 1;
  if (ws_size > fixed) {
    size_t av = (ws_size - fixed) / perCh;
    cg = (av < 1) ? 1 : (av > 16 ? 16 : (int)av);
  }

  float2* spec = (float2*)ws;
  __hip_bfloat16* xs = (__hip_bfloat16*)(ws + specBytes);
  __hip_bfloat16* ms = (__hip_bfloat16*)(ws + specBytes + xsBytes);
  __hip_bfloat16* Bst = (__hip_bfloat16*)(ws + fixed);
  __hip_bfloat16* X0 = Bst + (size_t)cg * SETSTR;
  __hip_bfloat16* X0T = X0 + (size_t)cg * SETSTR;
  __hip_bfloat16* X1 = X0T + (size_t)cg * SETSTR;
  __hip_bfloat16* X1T = X1 + (size_t)cg * SETSTR;
  float2* P0 = (float2*)(X1T + (size_t)cg * SETSTR);
  float2* P1 = P0 + (size_t)cg * MAPSZ;

  spectrum_kernel<<<dim3(32), dim3(576), 0, stream>>>(sig, spec);
  prep_x<<<dim3((8192 * 52 + 255) / 256), dim3(256), 0, stream>>>(x, xs);
  pad_m<<<dim3(512), dim3(256), 0, stream>>>(ms);

  const float scale = 1.f / 256.f;  // s = 8 squarings
  for (int c0 = 0; c0 < 16; c0 += cg) {
    int g = (16 - c0 < cg) ? (16 - c0) : cg;
    buildBX<<<dim3(1296, g), dim3(256), 0, stream>>>(spec, Bst, X0, c0, scale);
    transpose4<<<dim3(9, 9, g), dim3(256), 0, stream>>>(X0, X0T);
    __hip_bfloat16 *xr = X0, *xt = X0T, *yr = X1, *yt = X1T;
    // Horner (Taylor order 5): X <- I + (B*X)/k, k=4..1. Only DT consumed until k=1.
    for (int k = 4; k >= 1; --k) {
      int wf = (k == 1) ? 3 : 2;
      cgemm_mfma<<<dim3(25 * g), dim3(512), 0, stream>>>(Bst, xt, yr, yt,
                                                         1.f / (float)k, 1.f, wf);
      __hip_bfloat16* tmp;
      tmp = xr; xr = yr; yr = tmp;
      tmp = xt; xt = yt; yt = tmp;
    }
    // 8 squarings; last one only needs row-major output (feeds passA)
    for (int t8 = 0; t8 < 8; ++t8) {
      int wf = (t8 == 7) ? 1 : 3;
      cgemm_mfma<<<dim3(25 * g), dim3(512), 0, stream>>>(xr, xt, yr, yt, 1.f, 0.f, wf);
      __hip_bfloat16* tmp;
      tmp = xr; xr = yr; yr = tmp;
      tmp = xt; xt = yt; yt = tmp;
    }
    passA<<<dim3(400, g), dim3(256), 0, stream>>>(xr, P0);
    passB<<<dim3(400, g), dim3(256), 0, stream>>>(P0, P1);
    passC<<<dim3(400, g), dim3(256), 0, stream>>>(P1, P0);
    passD<<<dim3(400, g), dim3(256), 0, stream>>>(P0, ms, c0);
  }

  out_mfma<<<dim3(32, 64), dim3(512), 0, stream>>>(xs, ms, out);
}